// Round 10
// baseline (140.867 us; speedup 1.0000x reference)
//
#include <hip/hip_runtime.h>

// CapsuleLayer: 32x32x16 bf16 MFMA. Wave = 32 channels x 32 positions x 9 taps.
// Block = 4 waves (128 ch) x 2 output rows; 4-row LDS tile staged once.
// Routing: per-capsule reduce = 8 in-register + ONE shfl_xor(32).
// Sizes: B=8, C=128, H=W=32, K=3, pad=1 -> oh=ow=32, NC=512, 3 routing iters.
//
// d_ws: wT bf16 [9][512][128] (k-contig) ; inT bf16 [8][34][34][128] padded+swizzled.
// Swizzle: within each 256B channel-block of padded cell w, byte ^= (w&15)<<4.

typedef __bf16 bf16x8 __attribute__((ext_vector_type(8)));
typedef float  f32x4  __attribute__((ext_vector_type(4)));
typedef float  f32x16 __attribute__((ext_vector_type(16)));

#define NC    512
#define CIN   128
#define HW    32
#define INT_H 34
#define INT_W 34
#define ROWB  (INT_W * 256)          // 8704 B per padded row
#define WT_ELEMS (9 * NC * CIN)

// ---- fused prepass: blocks [0,288) -> wT ; [288, 866) -> inT (incl. borders) ----
__global__ __launch_bounds__(256)
void prepass(const float* __restrict__ in, const float* __restrict__ wgt,
             __bf16* __restrict__ wT, __bf16* __restrict__ inT) {
    const int t = threadIdx.x;
    if (blockIdx.x < 288) {
        int g   = blockIdx.x * 256 + t;     // 73728
        int n   = g & 511;
        int cb  = (g >> 9) & 15;
        int tap = g >> 13;
        bf16x8 v;
        #pragma unroll
        for (int k = 0; k < 8; k++)
            v[k] = (__bf16)wgt[(tap * CIN + cb * 8 + k) * NC + n];
        *(bf16x8*)(wT + ((size_t)tap * NC + n) * CIN + cb * 8) = v;
    } else {
        int g    = (blockIdx.x - 288) * 256 + t;   // 147968 = 8*34*34*16
        int cb   = g & 15;
        int cell = g >> 4;
        int w    = cell % INT_W;
        int rest = cell / INT_W;
        int h    = rest % INT_H;
        int b    = rest / INT_H;
        bf16x8 v;
        #pragma unroll
        for (int k = 0; k < 8; k++) v[k] = (__bf16)0.0f;
        if (h >= 1 && h <= 32 && w >= 1 && w <= 32) {
            #pragma unroll
            for (int k = 0; k < 8; k++)
                v[k] = (__bf16)in[((b * CIN + cb * 8 + k) * HW + (h - 1)) * HW + (w - 1)];
        }
        int within = (cb * 16) ^ ((w & 15) << 4);
        *(bf16x8*)((char*)inT + (size_t)(b * INT_H + h) * ROWB + w * 256 + within) = v;
    }
}

// ---- main ----
__global__ __launch_bounds__(256, 2)
void caps_main(const __bf16* __restrict__ wT, const __bf16* __restrict__ inT,
               const float* __restrict__ bias, float* __restrict__ out) {
    __shared__ __attribute__((aligned(16))) unsigned char tile[4 * ROWB];  // 34816 B

    const int x    = blockIdx.x;          // 512 blocks
    const int nblk = x & 3;               // 4 channel groups of 128
    const int hg   = (x >> 2) & 15;       // 16 h-groups of 2 rows
    const int b    = x >> 6;
    const int h0   = hg * 2;              // first output row (= first padded row needed)
    const int t    = threadIdx.x;
    const int lane = t & 63;
    const int wm   = t >> 6;
    const int l31  = lane & 31;
    const int lk   = lane >> 5;           // k-group (0/1)
    const int nb   = nblk * 128 + wm * 32;   // wave's base output channel

    // ---- stage padded rows h0..h0+3 into LDS (once; single barrier) ----
    {
        const char* ibase = (const char*)inT + (size_t)(b * INT_H + h0) * ROWB;
        #pragma unroll
        for (int row = 0; row < 4; row++) {
            const char* src = ibase + (size_t)row * ROWB;
            unsigned char* dst = tile + row * ROWB;
            int c = wm * 2;
            __builtin_amdgcn_global_load_lds((const unsigned*)(src + c * 1024 + lane * 16),
                                             (unsigned*)(dst + c * 1024), 16, 0, 0);
            __builtin_amdgcn_global_load_lds((const unsigned*)(src + (c + 1) * 1024 + lane * 16),
                                             (unsigned*)(dst + (c + 1) * 1024), 16, 0, 0);
            if (wm == 3 && lane < 32)
                __builtin_amdgcn_global_load_lds((const unsigned*)(src + 8192 + lane * 16),
                                                 (unsigned*)(dst + 8192), 16, 0, 0);
        }
    }
    __syncthreads();

    #pragma unroll 1
    for (int r = 0; r < 2; ++r) {
        // ---- acc init from bias: reg -> channel row (reg&3)+8*(reg>>2)+4*lk ----
        f32x16 acc[9];
        #pragma unroll
        for (int tap = 0; tap < 9; tap++) {
            #pragma unroll
            for (int q = 0; q < 4; q++) {
                f32x4 bv = *(const f32x4*)(bias + tap * NC + nb + lk * 4 + q * 8);
                acc[tap][q * 4 + 0] = bv[0];
                acc[tap][q * 4 + 1] = bv[1];
                acc[tap][q * 4 + 2] = bv[2];
                acc[tap][q * 4 + 3] = bv[3];
            }
        }

        // ---- GEMM: 9 taps x K=128 (8 chunks of 16) ----
        const int pos0 = l31;                   // output w = l31
        #pragma unroll
        for (int i = 0; i < 3; i++) {
            const unsigned char* rowp = tile + (r + i) * ROWB;
            #pragma unroll
            for (int j = 0; j < 3; j++) {
                const int tap = i * 3 + j;
                const int pos = j + pos0;       // padded col, 0..33
                const unsigned char* bp = rowp + pos * 256;
                const int sw = (pos & 15) << 4;
                const __bf16* ap = wT + (size_t)(tap * NC + nb + l31) * CIN + lk * 8;
                #pragma unroll
                for (int kk = 0; kk < 8; kk++) {
                    bf16x8 a  = *(const bf16x8*)(ap + kk * 16);
                    bf16x8 bv = *(const bf16x8*)(bp + (((kk * 32) + lk * 16) ^ sw));
                    acc[tap] = __builtin_amdgcn_mfma_f32_32x32x16_bf16(a, bv, acc[tap], 0, 0, 0);
                }
            }
        }

        // ---- routing: capsule A = regs 0..7, capsule B = regs 8..15 ----
        f32x16 o = acc[0];
        #pragma unroll
        for (int tap = 1; tap < 9; tap++) o += acc[tap];
        o = o * (1.0f / 9.0f);

        #pragma unroll
        for (int it = 0; it < 3; it++) {
            float cwa[9], cwb[9];
            float Sa = 0.f, Sb = 0.f;
            #pragma unroll
            for (int tap = 0; tap < 9; tap++) {
                float d2a = 0.f, d2b = 0.f;
                #pragma unroll
                for (int e = 0; e < 8; e++) {
                    float d = o[e] - acc[tap][e];
                    d2a = fmaf(d, d, d2a);
                }
                #pragma unroll
                for (int e = 8; e < 16; e++) {
                    float d = o[e] - acc[tap][e];
                    d2b = fmaf(d, d, d2b);
                }
                d2a += __shfl_xor(d2a, 32);
                d2b += __shfl_xor(d2b, 32);
                float ra = __builtin_amdgcn_rsqf(d2a + 1e-4f);
                float rb = __builtin_amdgcn_rsqf(d2b + 1e-4f);
                cwa[tap] = ra;  Sa += ra;
                cwb[tap] = rb;  Sb += rb;
            }
            float inva = __builtin_amdgcn_rcpf(Sa);
            float invb = __builtin_amdgcn_rcpf(Sb);
            f32x16 on;
            #pragma unroll
            for (int e = 0; e < 8; e++)  on[e] = acc[0][e] * cwa[0];
            #pragma unroll
            for (int e = 8; e < 16; e++) on[e] = acc[0][e] * cwb[0];
            #pragma unroll
            for (int tap = 1; tap < 9; tap++) {
                #pragma unroll
                for (int e = 0; e < 8; e++)  on[e] = fmaf(acc[tap][e], cwa[tap], on[e]);
                #pragma unroll
                for (int e = 8; e < 16; e++) on[e] = fmaf(acc[tap][e], cwb[tap], on[e]);
            }
            #pragma unroll
            for (int e = 0; e < 8; e++)  o[e] = on[e] * inva;
            #pragma unroll
            for (int e = 8; e < 16; e++) o[e] = on[e] * invb;
        }

        // ---- store: out[b][n][hr][w], n = nb + (reg&3)+8*(reg>>2)+4*lk, w = l31 ----
        const int hr = h0 + r;
        #pragma unroll
        for (int reg = 0; reg < 16; reg++) {
            int n = nb + (reg & 3) + 8 * (reg >> 2) + 4 * lk;
            out[((size_t)(b * NC + n) * HW + hr) * HW + l31] = o[reg];
        }
    }
}

extern "C" void kernel_launch(void* const* d_in, const int* in_sizes, int n_in,
                              void* d_out, int out_size, void* d_ws, size_t ws_size,
                              hipStream_t stream) {
    const float* in   = (const float*)d_in[0];
    const float* wgt  = (const float*)d_in[1];
    const float* bias = (const float*)d_in[2];
    float* out = (float*)d_out;

    __bf16* wT  = (__bf16*)d_ws;
    __bf16* inT = wT + WT_ELEMS;

    prepass<<<866, 256, 0, stream>>>(in, wgt, wT, inT);

    caps_main<<<512, 256, 0, stream>>>(wT, inT, bias, out);
}